// Round 1
// baseline (1141.120 us; speedup 1.0000x reference)
//
#include <hip/hip_runtime.h>
#include <hip/hip_bf16.h>
#include <stdint.h>

typedef unsigned short u16;

#define K_DIM 4096
#define N_DIM 16384

// ---- 8-phase 256^2 geometry
#define BM 256
#define BN 256
#define BK 64
#define NT (K_DIM / BK)  // 64 K-tiles
#define HALF_ELEMS 8192  // 128 rows * 64 cols

typedef __attribute__((ext_vector_type(4))) float f32x4;
typedef __attribute__((ext_vector_type(16))) float f32x16;
typedef __attribute__((ext_vector_type(8))) short bf16x8;

#define GLOAD_LDS16(g, l)                                                      \
  __builtin_amdgcn_global_load_lds(                                            \
      (const __attribute__((address_space(1))) void*)(g),                      \
      (__attribute__((address_space(3))) void*)(l), 16, 0, 0)

#define SFENCE() __builtin_amdgcn_sched_barrier(0)
#define CFENCE() asm volatile("" ::: "memory")
#define BARRIER()                                                              \
  do {                                                                         \
    SFENCE();                                                                  \
    CFENCE();                                                                  \
    __builtin_amdgcn_s_barrier();                                              \
    CFENCE();                                                                  \
    SFENCE();                                                                  \
  } while (0)
#define VMCNT(n) asm volatile("s_waitcnt vmcnt(" #n ")" ::: "memory")

// int32 in [-127,127] -> bf16 exact
__device__ __forceinline__ u16 i32_to_bf16(int v) {
  return (u16)(__float_as_uint((float)v) >> 16);
}
__device__ __forceinline__ u16 f32_to_bf16(float f) {
  __hip_bfloat16 h = __float2bfloat16(f);
  return *(u16*)&h;
}

__global__ void wconvert_kernel(const int* __restrict__ w,
                                u16* __restrict__ out, int n4) {
  int idx = blockIdx.x * blockDim.x + threadIdx.x;
  int stride = gridDim.x * blockDim.x;
  const int4* w4 = (const int4*)w;
  ushort4* o4 = (ushort4*)out;
  for (int i = idx; i < n4; i += stride) {
    int4 v = w4[i];
    ushort4 o;
    o.x = i32_to_bf16(v.x);
    o.y = i32_to_bf16(v.y);
    o.z = i32_to_bf16(v.z);
    o.w = i32_to_bf16(v.w);
    o4[i] = o;
  }
}

__global__ void xconvert_kernel(const float* __restrict__ x,
                                u16* __restrict__ out, int n4) {
  int idx = blockIdx.x * blockDim.x + threadIdx.x;
  int stride = gridDim.x * blockDim.x;
  const float4* x4 = (const float4*)x;
  ushort4* o4 = (ushort4*)out;
  for (int i = idx; i < n4; i += stride) {
    float4 v = x4[i];
    ushort4 o;
    o.x = f32_to_bf16(v.x);
    o.y = f32_to_bf16(v.y);
    o.z = f32_to_bf16(v.z);
    o.w = f32_to_bf16(v.w);
    o4[i] = o;
  }
}

// Stage one half-tile (128 rows x 64 k, bf16, 16KB) global->LDS.
// LDS dest is LINEAR (gload_lds writes base + lane*16); the T2 st-swizzle is
// applied by permuting the GLOBAL source 16B-unit: logical unit = lin ^ (row&7).
// Read side applies the same XOR -> bank-conflict-free ds_read_b128.
__device__ __forceinline__ void stage_half(const u16* __restrict__ src,
                                           u16* lds_half, int t) {
#pragma unroll
  for (int c = 0; c < 2; ++c) {
    int e = c * 4096 + t * 8;                 // per-lane linear u16 offset
    int row = c * 64 + (t >> 3);              // 0..127
    int usw = (t & 7) ^ ((t >> 3) & 7);       // lin-unit ^ (row&7)
    int base = __builtin_amdgcn_readfirstlane(e);  // wave-uniform LDS base
    GLOAD_LDS16(src + (size_t)row * K_DIM + usw * 8, lds_half + base);
  }
}

// swizzled fragment read: tile row r (0..255), 16B-unit u (0..7)
__device__ __forceinline__ bf16x8 frag(const u16* sbuf, int r, int u) {
  return *(const bf16x8*)&sbuf[r * 64 + ((u ^ (r & 7)) << 3)];
}

// C[M,N] = X[M,K] * W[N,K]^T ; y = acc*scale[n] + bias[n], f32 out.
// 256x256 tile, BK=64, 8 waves (2M x 4N), per-wave 128x64 output,
// 8-phase K-loop (2 K-tiles/iter), counted vmcnt(6), setprio, src-swizzled LDS.
// MFMA shape: 32x32x16 bf16 (higher pipe ceiling than 16x16x32, half the
// instruction count). Per wave: 4x2 grid of 32x32 tiles, acc = 8 x f32x16.
__global__ __launch_bounds__(512, 2) void qgemm8_kernel(
    const u16* __restrict__ Xb,   // bf16 [M][K]
    const u16* __restrict__ Wb,   // bf16 [N][K]
    const float* __restrict__ S,  // f32 [N]
    const float* __restrict__ Bv, // f32 [N]
    float* __restrict__ Y,        // f32 [M][N]
    int M) {
  extern __shared__ u16 lds[];
  u16* sA0 = lds;             // buf0 A [256][64]
  u16* sB0 = lds + 16384;     // buf0 B
  u16* sA1 = lds + 32768;     // buf1 A
  u16* sB1 = lds + 49152;     // buf1 B

  const int t = threadIdx.x;
  // XCD-aware swizzle (nwg = 2048, divisible by 8)
  const int bid = blockIdx.x;
  const int cpx = gridDim.x >> 3;
  const int swz = (bid & 7) * cpx + (bid >> 3);
  const int n0 = (swz & 63) * BN;  // 64 n-blocks
  const int m0 = (swz >> 6) * BM;

  const int lane = t & 63;
  const int wid = t >> 6;   // 0..7
  const int r32 = lane & 31;   // row/col within 32x32 tile
  const int hi1 = lane >> 5;   // k-half selector (0..1)
  const int wm = wid >> 2;  // 0..1 -> rows wm*128..+127
  const int wn = wid & 3;   // 0..3 -> cols wn*64..+63

  const u16* Asrc = Xb + (size_t)m0 * K_DIM;
  const u16* Bsrc = Wb + (size_t)n0 * K_DIM;

  f32x16 acc[4][2] = {};  // [row-tile 0..3][col-tile 0..1]
  bf16x8 aT[8], bT[8];    // [rt*4+ks] / [ct*4+ks], ks = 0..3 (K=16 steps)

  // 32x32x16 operand layout: lane holds row/col = lane&31,
  // k = (lane>>5)*8 + j  -> 16B unit u = ks*2 + hi1 within the 64-k row.
#define LOAD_B(sb)                                                             \
  _Pragma("unroll") for (int ct = 0; ct < 2; ++ct)                             \
  _Pragma("unroll") for (int ks = 0; ks < 4; ++ks)                             \
      bT[ct * 4 + ks] = frag(sb, wn * 64 + ct * 32 + r32, ks * 2 + hi1);

#define LOAD_A(sa, HB)                                                         \
  _Pragma("unroll") for (int rt = 0; rt < 2; ++rt)                             \
  _Pragma("unroll") for (int ks = 0; ks < 4; ++ks)                             \
      aT[rt * 4 + ks] =                                                        \
          frag(sa, wm * 128 + ((HB) + rt) * 32 + r32, ks * 2 + hi1);

// one quadrant: 64 rows (HB half) x 32 cols (CT) x K=64 -> 8 MFMAs
#define QUAD(HB, CT)                                                           \
  do {                                                                         \
    __builtin_amdgcn_s_setprio(1);                                             \
    _Pragma("unroll") for (int ks = 0; ks < 4; ++ks)                           \
    _Pragma("unroll") for (int rt = 0; rt < 2; ++rt)                           \
        acc[(HB) + rt][CT] =                                                   \
            __builtin_amdgcn_mfma_f32_32x32x16_bf16(                           \
                aT[rt * 4 + ks], bT[(CT) * 4 + ks], acc[(HB) + rt][CT],        \
                0, 0, 0);                                                      \
    __builtin_amdgcn_s_setprio(0);                                             \
  } while (0)

  // ---- prologue: stage T0 fully (4 halves), then T1's B0,B1,A0 (3 halves)
  stage_half(Bsrc, sB0, t);
  stage_half(Bsrc + 128 * K_DIM, sB0 + HALF_ELEMS, t);
  stage_half(Asrc, sA0, t);
  stage_half(Asrc + 128 * K_DIM, sA0 + HALF_ELEMS, t);
  VMCNT(4);
  stage_half(Bsrc + BK, sB1, t);
  stage_half(Bsrc + 128 * K_DIM + BK, sB1 + HALF_ELEMS, t);
  stage_half(Asrc + BK, sA1, t);
  VMCNT(6);  // T0's 4 halves landed; 3 halves (T1 partial) in flight
  BARRIER();

  // ---- main loop: iteration i computes K-tiles 2i (buf0) and 2i+1 (buf1)
  for (int i = 0; i < NT / 2; ++i) {
    const int t1k = (2 * i + 1) * BK;
    const int tn0k = (2 * i + 2) * BK;
    const int tn1k = (2 * i + 3) * BK;
    const bool gn0 = (2 * i + 2) < NT;
    const bool gn1 = (2 * i + 3) < NT;

    // P1: all B + A-lo of T0(buf0); stage A1 of T1 -> buf1
    LOAD_B(sB0);
    LOAD_A(sA0, 0);
    stage_half(Asrc + 128 * K_DIM + t1k, sA1 + HALF_ELEMS, t);
    BARRIER();
    QUAD(0, 0);
    BARRIER();

    // P2: stage B0 of Tn0 -> buf0 (B(buf0) LDS dead after P1)
    if (gn0) stage_half(Bsrc + tn0k, sB0, t);
    BARRIER();
    QUAD(0, 1);
    BARRIER();

    // P3: A-hi of T0; stage B1 of Tn0
    LOAD_A(sA0, 2);
    if (gn0) stage_half(Bsrc + 128 * K_DIM + tn0k, sB0 + HALF_ELEMS, t);
    BARRIER();
    QUAD(2, 0);
    BARRIER();

    // P4: stage A0 of Tn0 (A(buf0) dead after P3); counted drain AFTER the
    // MFMAs (stall point moved behind the compute, still before end barrier)
    if (gn0) stage_half(Asrc + tn0k, sA0, t);
    BARRIER();
    QUAD(2, 1);
    if (gn0) {
      VMCNT(6);  // guarantees T1 fully resident (incl. P1's A1)
    } else {
      VMCNT(0);  // tail: nothing counted behind, drain fully
    }
    BARRIER();

    // P5: all B + A-lo of T1(buf1); stage A1 of Tn0 -> buf0
    LOAD_B(sB1);
    LOAD_A(sA1, 0);
    if (gn0) stage_half(Asrc + 128 * K_DIM + tn0k, sA0 + HALF_ELEMS, t);
    BARRIER();
    QUAD(0, 0);
    BARRIER();

    // P6: stage B0 of Tn1 -> buf1 (B(buf1) dead after P5)
    if (gn1) stage_half(Bsrc + tn1k, sB1, t);
    BARRIER();
    QUAD(0, 1);
    BARRIER();

    // P7: A-hi of T1; stage B1 of Tn1
    LOAD_A(sA1, 2);
    if (gn1) stage_half(Bsrc + 128 * K_DIM + tn1k, sB1 + HALF_ELEMS, t);
    BARRIER();
    QUAD(2, 0);
    BARRIER();

    // P8: stage A0 of Tn1 (A(buf1) dead after P7); counted drain after MFMAs
    if (gn1) stage_half(Asrc + tn1k, sA1, t);
    BARRIER();
    QUAD(2, 1);
    if (gn1) {
      VMCNT(6);  // guarantees Tn0 fully resident for next iteration
    } else {
      VMCNT(0);
    }
    BARRIER();
  }

  // ---- epilogue: y = acc * scale[n] + bias[n], f32 store
  // 32x32 C/D layout: col = lane&31, row = (reg&3) + 8*(reg>>2) + 4*(lane>>5)
#pragma unroll
  for (int ct = 0; ct < 2; ++ct) {
    int n = n0 + wn * 64 + ct * 32 + r32;
    float sc = S[n];
    float bv = Bv[n];
#pragma unroll
    for (int mi = 0; mi < 4; ++mi) {
#pragma unroll
      for (int reg = 0; reg < 16; ++reg) {
        int m = m0 + wm * 128 + mi * 32 + (reg & 3) + 8 * (reg >> 2) + 4 * hi1;
        Y[(size_t)m * N_DIM + n] = acc[mi][ct][reg] * sc + bv;
      }
    }
  }
#undef LOAD_A
#undef LOAD_B
#undef QUAD
}

// ---- fallback (ws too small): serial 128^2 with inline convert (r3-verified
// structure, minus pre-conversion)
__global__ __launch_bounds__(256) void qgemm_fb_kernel(
    const float* __restrict__ Xf, const int* __restrict__ Wi,
    const float* __restrict__ S, const float* __restrict__ Bv,
    float* __restrict__ Y, int M) {
  __shared__ u16 As[128 * 64];
  __shared__ u16 Bs[128 * 64];
  const int t = threadIdx.x;
  const int bid = blockIdx.x;
  const int n0 = (bid & 127) * 128;
  const int m0 = (bid >> 7) * 128;
  const int lane = t & 63;
  const int wid = t >> 6;
  const int r16 = lane & 15;
  const int hi4 = lane >> 4;
  const int wm = wid >> 1;
  const int wn = wid & 1;
  f32x4 acc[4][4] = {};
  for (int kt = 0; kt < K_DIM; kt += 64) {
#pragma unroll
    for (int c = 0; c < 8; ++c) {
      int h = c * 1024 + t * 4;
      int row = h >> 6;
      int col = h & 63;
      float4 v = *(const float4*)(Xf + (size_t)(m0 + row) * K_DIM + kt + col);
      ushort4 o;
      o.x = f32_to_bf16(v.x); o.y = f32_to_bf16(v.y);
      o.z = f32_to_bf16(v.z); o.w = f32_to_bf16(v.w);
      *(ushort4*)&As[h] = o;
      int4 w = *(const int4*)(Wi + (size_t)(n0 + row) * K_DIM + kt + col);
      ushort4 ow;
      ow.x = i32_to_bf16(w.x); ow.y = i32_to_bf16(w.y);
      ow.z = i32_to_bf16(w.z); ow.w = i32_to_bf16(w.w);
      *(ushort4*)&Bs[h] = ow;
    }
    __syncthreads();
#pragma unroll
    for (int kk = 0; kk < 64; kk += 32) {
      bf16x8 af[4], bf[4];
#pragma unroll
      for (int mi = 0; mi < 4; ++mi)
        af[mi] = *(const bf16x8*)&As[(wm * 64 + mi * 16 + r16) * 64 + kk + hi4 * 8];
#pragma unroll
      for (int ni = 0; ni < 4; ++ni)
        bf[ni] = *(const bf16x8*)&Bs[(wn * 64 + ni * 16 + r16) * 64 + kk + hi4 * 8];
#pragma unroll
      for (int mi = 0; mi < 4; ++mi)
#pragma unroll
        for (int ni = 0; ni < 4; ++ni)
          acc[mi][ni] = __builtin_amdgcn_mfma_f32_16x16x32_bf16(
              af[mi], bf[ni], acc[mi][ni], 0, 0, 0);
    }
    __syncthreads();
  }
#pragma unroll
  for (int ni = 0; ni < 4; ++ni) {
    int n = n0 + wn * 64 + ni * 16 + r16;
    float sc = S[n], bv = Bv[n];
#pragma unroll
    for (int mi = 0; mi < 4; ++mi)
#pragma unroll
      for (int r = 0; r < 4; ++r) {
        int m = m0 + wm * 64 + mi * 16 + hi4 * 4 + r;
        Y[(size_t)m * N_DIM + n] = acc[mi][ni][r] * sc + bv;
      }
  }
}

extern "C" void kernel_launch(void* const* d_in, const int* in_sizes, int n_in,
                              void* d_out, int out_size, void* d_ws,
                              size_t ws_size, hipStream_t stream) {
  const float* x = (const float*)d_in[0];  // fp16 promoted to f32 by harness
  const int* wgt = (const int*)d_in[1];    // int8 promoted to int32
  const float* s = (const float*)d_in[2];
  const float* b = (const float*)d_in[3];
  float* y = (float*)d_out;

  const int M = in_sizes[0] / K_DIM;  // 8192
  const size_t wcount = (size_t)N_DIM * K_DIM;
  const size_t xcount = (size_t)in_sizes[0];
  const size_t need = (wcount + xcount) * sizeof(u16);

  if (ws_size >= need && (M % BM) == 0) {
    u16* wb = (u16*)d_ws;
    u16* xb = wb + wcount;
    wconvert_kernel<<<2048, 256, 0, stream>>>(wgt, wb, (int)(wcount / 4));
    xconvert_kernel<<<2048, 256, 0, stream>>>(x, xb, (int)(xcount / 4));
    hipFuncSetAttribute((const void*)qgemm8_kernel,
                        hipFuncAttributeMaxDynamicSharedMemorySize, 131072);
    dim3 grid((N_DIM / BN) * (M / BM));  // 2048
    qgemm8_kernel<<<grid, 512, 131072, stream>>>(xb, wb, s, b, y, M);
  } else {
    dim3 grid((N_DIM / 128) * (M / 128));
    qgemm_fb_kernel<<<grid, 256, 0, stream>>>(x, wgt, s, b, y, M);
  }
}

// Round 2
// 1078.725 us; speedup vs baseline: 1.0578x; 1.0578x over previous
//
#include <hip/hip_runtime.h>
#include <hip/hip_bf16.h>
#include <stdint.h>

typedef unsigned short u16;

#define K_DIM 4096
#define N_DIM 16384

// ---- 8-phase 256^2 geometry
#define BM 256
#define BN 256
#define BK 64
#define NT (K_DIM / BK)  // 64 K-tiles
#define HALF_ELEMS 8192  // 128 rows * 64 cols

typedef __attribute__((ext_vector_type(4))) float f32x4;
typedef __attribute__((ext_vector_type(16))) float f32x16;
typedef __attribute__((ext_vector_type(8))) short bf16x8;

#define GLOAD_LDS16(g, l)                                                      \
  __builtin_amdgcn_global_load_lds(                                            \
      (const __attribute__((address_space(1))) void*)(g),                      \
      (__attribute__((address_space(3))) void*)(l), 16, 0, 0)

#define SFENCE() __builtin_amdgcn_sched_barrier(0)
#define CFENCE() asm volatile("" ::: "memory")
#define BARRIER()                                                              \
  do {                                                                         \
    SFENCE();                                                                  \
    CFENCE();                                                                  \
    __builtin_amdgcn_s_barrier();                                              \
    CFENCE();                                                                  \
    SFENCE();                                                                  \
  } while (0)
#define VMCNT(n) asm volatile("s_waitcnt vmcnt(" #n ")" ::: "memory")

// int32 in [-127,127] -> bf16 exact
__device__ __forceinline__ u16 i32_to_bf16(int v) {
  return (u16)(__float_as_uint((float)v) >> 16);
}
__device__ __forceinline__ u16 f32_to_bf16(float f) {
  __hip_bfloat16 h = __float2bfloat16(f);
  return *(u16*)&h;
}

__global__ void wconvert_kernel(const int* __restrict__ w,
                                u16* __restrict__ out, int n4) {
  int idx = blockIdx.x * blockDim.x + threadIdx.x;
  int stride = gridDim.x * blockDim.x;
  const int4* w4 = (const int4*)w;
  ushort4* o4 = (ushort4*)out;
  for (int i = idx; i < n4; i += stride) {
    int4 v = w4[i];
    ushort4 o;
    o.x = i32_to_bf16(v.x);
    o.y = i32_to_bf16(v.y);
    o.z = i32_to_bf16(v.z);
    o.w = i32_to_bf16(v.w);
    o4[i] = o;
  }
}

__global__ void xconvert_kernel(const float* __restrict__ x,
                                u16* __restrict__ out, int n4) {
  int idx = blockIdx.x * blockDim.x + threadIdx.x;
  int stride = gridDim.x * blockDim.x;
  const float4* x4 = (const float4*)x;
  ushort4* o4 = (ushort4*)out;
  for (int i = idx; i < n4; i += stride) {
    float4 v = x4[i];
    ushort4 o;
    o.x = f32_to_bf16(v.x);
    o.y = f32_to_bf16(v.y);
    o.z = f32_to_bf16(v.z);
    o.w = f32_to_bf16(v.w);
    o4[i] = o;
  }
}

// Stage one half-tile (128 rows x 64 k, bf16, 16KB) global->LDS.
// LDS dest is LINEAR (gload_lds writes base + lane*16); the st-swizzle is
// applied by permuting the GLOBAL source 16B-unit:
//   stored unit at LDS slot (row, lin) = lin ^ sigma(row),
//   sigma(row) = (row ^ (row>>2)) & 7.
// sigma folds row bits [4:2] in as well as [2:0] so that BOTH stride-1 and
// stride-4 row-sets inside one ds_read_b128 crossbar phase spread over all 8
// bank groups (the 32x32 frag read spans 32 rows at fixed k-unit; with the
// old sigma=row&7 its strided-lane phases collapsed to 4 bank groups ->
// measured 4-way conflict, 1.0e8 cycles in round 1).
__device__ __forceinline__ void stage_half(const u16* __restrict__ src,
                                           u16* lds_half, int t) {
#pragma unroll
  for (int c = 0; c < 2; ++c) {
    int e = c * 4096 + t * 8;                 // per-lane linear u16 offset
    // row = c*64 + (t>>3); sigma(row) = ((t>>3) ^ (t>>5)) & 7 (c*64 drops out)
    int row = c * 64 + (t >> 3);              // 0..127
    int usw = (t & 7) ^ (((t >> 3) ^ (t >> 5)) & 7);  // lin ^ sigma(row)
    int base = __builtin_amdgcn_readfirstlane(e);  // wave-uniform LDS base
    GLOAD_LDS16(src + (size_t)row * K_DIM + usw * 8, lds_half + base);
  }
}

// swizzled fragment read: tile row r (0..255), 16B-unit u (0..7)
__device__ __forceinline__ bf16x8 frag(const u16* sbuf, int r, int u) {
  return *(const bf16x8*)&sbuf[r * 64 + ((u ^ ((r ^ (r >> 2)) & 7)) << 3)];
}

// C[M,N] = X[M,K] * W[N,K]^T ; y = acc*scale[n] + bias[n], f32 out.
// 256x256 tile, BK=64, 8 waves (2M x 4N), per-wave 128x64 output,
// 8-phase K-loop (2 K-tiles/iter), counted vmcnt(6), setprio, src-swizzled LDS.
// MFMA shape: 32x32x16 bf16 (higher pipe ceiling than 16x16x32, half the
// instruction count). Per wave: 4x2 grid of 32x32 tiles, acc = 8 x f32x16.
__global__ __launch_bounds__(512, 2) void qgemm8_kernel(
    const u16* __restrict__ Xb,   // bf16 [M][K]
    const u16* __restrict__ Wb,   // bf16 [N][K]
    const float* __restrict__ S,  // f32 [N]
    const float* __restrict__ Bv, // f32 [N]
    float* __restrict__ Y,        // f32 [M][N]
    int M) {
  extern __shared__ u16 lds[];
  u16* sA0 = lds;             // buf0 A [256][64]
  u16* sB0 = lds + 16384;     // buf0 B
  u16* sA1 = lds + 32768;     // buf1 A
  u16* sB1 = lds + 49152;     // buf1 B

  const int t = threadIdx.x;
  // XCD-aware swizzle (nwg = 2048, divisible by 8)
  const int bid = blockIdx.x;
  const int cpx = gridDim.x >> 3;
  const int swz = (bid & 7) * cpx + (bid >> 3);
  const int n0 = (swz & 63) * BN;  // 64 n-blocks
  const int m0 = (swz >> 6) * BM;

  const int lane = t & 63;
  const int wid = t >> 6;   // 0..7
  const int r32 = lane & 31;   // row/col within 32x32 tile
  const int hi1 = lane >> 5;   // k-half selector (0..1)
  const int wm = wid >> 2;  // 0..1 -> rows wm*128..+127
  const int wn = wid & 3;   // 0..3 -> cols wn*64..+63

  const u16* Asrc = Xb + (size_t)m0 * K_DIM;
  const u16* Bsrc = Wb + (size_t)n0 * K_DIM;

  f32x16 acc[4][2] = {};  // [row-tile 0..3][col-tile 0..1]
  bf16x8 aT[8], bT[8];    // [rt*4+ks] / [ct*4+ks], ks = 0..3 (K=16 steps)

  // 32x32x16 operand layout: lane holds row/col = lane&31,
  // k = (lane>>5)*8 + j  -> 16B unit u = ks*2 + hi1 within the 64-k row.
#define LOAD_B(sb)                                                             \
  _Pragma("unroll") for (int ct = 0; ct < 2; ++ct)                             \
  _Pragma("unroll") for (int ks = 0; ks < 4; ++ks)                             \
      bT[ct * 4 + ks] = frag(sb, wn * 64 + ct * 32 + r32, ks * 2 + hi1);

#define LOAD_A(sa, HB)                                                         \
  _Pragma("unroll") for (int rt = 0; rt < 2; ++rt)                             \
  _Pragma("unroll") for (int ks = 0; ks < 4; ++ks)                             \
      aT[rt * 4 + ks] =                                                        \
          frag(sa, wm * 128 + ((HB) + rt) * 32 + r32, ks * 2 + hi1);

// one quadrant: 64 rows (HB half) x 32 cols (CT) x K=64 -> 8 MFMAs
#define QUAD(HB, CT)                                                           \
  do {                                                                         \
    __builtin_amdgcn_s_setprio(1);                                             \
    _Pragma("unroll") for (int ks = 0; ks < 4; ++ks)                           \
    _Pragma("unroll") for (int rt = 0; rt < 2; ++rt)                           \
        acc[(HB) + rt][CT] =                                                   \
            __builtin_amdgcn_mfma_f32_32x32x16_bf16(                           \
                aT[rt * 4 + ks], bT[(CT) * 4 + ks], acc[(HB) + rt][CT],        \
                0, 0, 0);                                                      \
    __builtin_amdgcn_s_setprio(0);                                             \
  } while (0)

  // ---- prologue: stage T0 fully (4 halves), then T1's B0,B1,A0 (3 halves)
  stage_half(Bsrc, sB0, t);
  stage_half(Bsrc + 128 * K_DIM, sB0 + HALF_ELEMS, t);
  stage_half(Asrc, sA0, t);
  stage_half(Asrc + 128 * K_DIM, sA0 + HALF_ELEMS, t);
  VMCNT(4);
  stage_half(Bsrc + BK, sB1, t);
  stage_half(Bsrc + 128 * K_DIM + BK, sB1 + HALF_ELEMS, t);
  stage_half(Asrc + BK, sA1, t);
  VMCNT(6);  // T0's 4 halves landed; 3 halves (T1 partial) in flight
  BARRIER();

  // ---- main loop: iteration i computes K-tiles 2i (buf0) and 2i+1 (buf1)
  for (int i = 0; i < NT / 2; ++i) {
    const int t1k = (2 * i + 1) * BK;
    const int tn0k = (2 * i + 2) * BK;
    const int tn1k = (2 * i + 3) * BK;
    const bool gn0 = (2 * i + 2) < NT;
    const bool gn1 = (2 * i + 3) < NT;

    // P1: all B + A-lo of T0(buf0); stage A1 of T1 -> buf1
    LOAD_B(sB0);
    LOAD_A(sA0, 0);
    stage_half(Asrc + 128 * K_DIM + t1k, sA1 + HALF_ELEMS, t);
    BARRIER();
    QUAD(0, 0);
    BARRIER();

    // P2: stage B0 of Tn0 -> buf0 (B(buf0) LDS dead after P1)
    if (gn0) stage_half(Bsrc + tn0k, sB0, t);
    BARRIER();
    QUAD(0, 1);
    BARRIER();

    // P3: A-hi of T0; stage B1 of Tn0
    LOAD_A(sA0, 2);
    if (gn0) stage_half(Bsrc + 128 * K_DIM + tn0k, sB0 + HALF_ELEMS, t);
    BARRIER();
    QUAD(2, 0);
    BARRIER();

    // P4: stage A0 of Tn0 (A(buf0) dead after P3); counted drain AFTER the
    // MFMAs (stall point moved behind the compute, still before end barrier)
    if (gn0) stage_half(Asrc + tn0k, sA0, t);
    BARRIER();
    QUAD(2, 1);
    if (gn0) {
      VMCNT(6);  // guarantees T1 fully resident (incl. P1's A1)
    } else {
      VMCNT(0);  // tail: nothing counted behind, drain fully
    }
    BARRIER();

    // P5: all B + A-lo of T1(buf1); stage A1 of Tn0 -> buf0
    LOAD_B(sB1);
    LOAD_A(sA1, 0);
    if (gn0) stage_half(Asrc + 128 * K_DIM + tn0k, sA0 + HALF_ELEMS, t);
    BARRIER();
    QUAD(0, 0);
    BARRIER();

    // P6: stage B0 of Tn1 -> buf1 (B(buf1) dead after P5)
    if (gn1) stage_half(Bsrc + tn1k, sB1, t);
    BARRIER();
    QUAD(0, 1);
    BARRIER();

    // P7: A-hi of T1; stage B1 of Tn1
    LOAD_A(sA1, 2);
    if (gn1) stage_half(Bsrc + 128 * K_DIM + tn1k, sB1 + HALF_ELEMS, t);
    BARRIER();
    QUAD(2, 0);
    BARRIER();

    // P8: stage A0 of Tn1 (A(buf1) dead after P7); counted drain after MFMAs
    if (gn1) stage_half(Asrc + tn1k, sA1, t);
    BARRIER();
    QUAD(2, 1);
    if (gn1) {
      VMCNT(6);  // guarantees Tn0 fully resident for next iteration
    } else {
      VMCNT(0);
    }
    BARRIER();
  }

  // ---- epilogue: y = acc * scale[n] + bias[n], f32 store
  // 32x32 C/D layout: col = lane&31, row = (reg&3) + 8*(reg>>2) + 4*(lane>>5)
#pragma unroll
  for (int ct = 0; ct < 2; ++ct) {
    int n = n0 + wn * 64 + ct * 32 + r32;
    float sc = S[n];
    float bv = Bv[n];
#pragma unroll
    for (int mi = 0; mi < 4; ++mi) {
#pragma unroll
      for (int reg = 0; reg < 16; ++reg) {
        int m = m0 + wm * 128 + mi * 32 + (reg & 3) + 8 * (reg >> 2) + 4 * hi1;
        Y[(size_t)m * N_DIM + n] = acc[mi][ct][reg] * sc + bv;
      }
    }
  }
#undef LOAD_A
#undef LOAD_B
#undef QUAD
}

// ---- fallback (ws too small): serial 128^2 with inline convert (r3-verified
// structure, minus pre-conversion)
__global__ __launch_bounds__(256) void qgemm_fb_kernel(
    const float* __restrict__ Xf, const int* __restrict__ Wi,
    const float* __restrict__ S, const float* __restrict__ Bv,
    float* __restrict__ Y, int M) {
  __shared__ u16 As[128 * 64];
  __shared__ u16 Bs[128 * 64];
  const int t = threadIdx.x;
  const int bid = blockIdx.x;
  const int n0 = (bid & 127) * 128;
  const int m0 = (bid >> 7) * 128;
  const int lane = t & 63;
  const int wid = t >> 6;
  const int r16 = lane & 15;
  const int hi4 = lane >> 4;
  const int wm = wid >> 1;
  const int wn = wid & 1;
  f32x4 acc[4][4] = {};
  for (int kt = 0; kt < K_DIM; kt += 64) {
#pragma unroll
    for (int c = 0; c < 8; ++c) {
      int h = c * 1024 + t * 4;
      int row = h >> 6;
      int col = h & 63;
      float4 v = *(const float4*)(Xf + (size_t)(m0 + row) * K_DIM + kt + col);
      ushort4 o;
      o.x = f32_to_bf16(v.x); o.y = f32_to_bf16(v.y);
      o.z = f32_to_bf16(v.z); o.w = f32_to_bf16(v.w);
      *(ushort4*)&As[h] = o;
      int4 w = *(const int4*)(Wi + (size_t)(n0 + row) * K_DIM + kt + col);
      ushort4 ow;
      ow.x = i32_to_bf16(w.x); ow.y = i32_to_bf16(w.y);
      ow.z = i32_to_bf16(w.z); ow.w = i32_to_bf16(w.w);
      *(ushort4*)&Bs[h] = ow;
    }
    __syncthreads();
#pragma unroll
    for (int kk = 0; kk < 64; kk += 32) {
      bf16x8 af[4], bf[4];
#pragma unroll
      for (int mi = 0; mi < 4; ++mi)
        af[mi] = *(const bf16x8*)&As[(wm * 64 + mi * 16 + r16) * 64 + kk + hi4 * 8];
#pragma unroll
      for (int ni = 0; ni < 4; ++ni)
        bf[ni] = *(const bf16x8*)&Bs[(wn * 64 + ni * 16 + r16) * 64 + kk + hi4 * 8];
#pragma unroll
      for (int mi = 0; mi < 4; ++mi)
#pragma unroll
        for (int ni = 0; ni < 4; ++ni)
          acc[mi][ni] = __builtin_amdgcn_mfma_f32_16x16x32_bf16(
              af[mi], bf[ni], acc[mi][ni], 0, 0, 0);
    }
    __syncthreads();
  }
#pragma unroll
  for (int ni = 0; ni < 4; ++ni) {
    int n = n0 + wn * 64 + ni * 16 + r16;
    float sc = S[n], bv = Bv[n];
#pragma unroll
    for (int mi = 0; mi < 4; ++mi)
#pragma unroll
      for (int r = 0; r < 4; ++r) {
        int m = m0 + wm * 64 + mi * 16 + hi4 * 4 + r;
        Y[(size_t)m * N_DIM + n] = acc[mi][ni][r] * sc + bv;
      }
  }
}

extern "C" void kernel_launch(void* const* d_in, const int* in_sizes, int n_in,
                              void* d_out, int out_size, void* d_ws,
                              size_t ws_size, hipStream_t stream) {
  const float* x = (const float*)d_in[0];  // fp16 promoted to f32 by harness
  const int* wgt = (const int*)d_in[1];    // int8 promoted to int32
  const float* s = (const float*)d_in[2];
  const float* b = (const float*)d_in[3];
  float* y = (float*)d_out;

  const int M = in_sizes[0] / K_DIM;  // 8192
  const size_t wcount = (size_t)N_DIM * K_DIM;
  const size_t xcount = (size_t)in_sizes[0];
  const size_t need = (wcount + xcount) * sizeof(u16);

  if (ws_size >= need && (M % BM) == 0) {
    u16* wb = (u16*)d_ws;
    u16* xb = wb + wcount;
    wconvert_kernel<<<2048, 256, 0, stream>>>(wgt, wb, (int)(wcount / 4));
    xconvert_kernel<<<2048, 256, 0, stream>>>(x, xb, (int)(xcount / 4));
    hipFuncSetAttribute((const void*)qgemm8_kernel,
                        hipFuncAttributeMaxDynamicSharedMemorySize, 131072);
    dim3 grid((N_DIM / BN) * (M / BM));  // 2048
    qgemm8_kernel<<<grid, 512, 131072, stream>>>(xb, wb, s, b, y, M);
  } else {
    dim3 grid((N_DIM / 128) * (M / 128));
    qgemm_fb_kernel<<<grid, 256, 0, stream>>>(x, wgt, s, b, y, M);
  }
}

// Round 3
// 1077.360 us; speedup vs baseline: 1.0592x; 1.0013x over previous
//
#include <hip/hip_runtime.h>
#include <hip/hip_bf16.h>
#include <stdint.h>

typedef unsigned short u16;

#define K_DIM 4096
#define N_DIM 16384

// ---- merged 4-phase 256^2 geometry
#define BM 256
#define BN 256
#define BK 64
#define NT (K_DIM / BK)  // 64 K-tiles
#define HALF_ELEMS 8192  // 128 rows * 64 cols

typedef __attribute__((ext_vector_type(4))) float f32x4;
typedef __attribute__((ext_vector_type(16))) float f32x16;
typedef __attribute__((ext_vector_type(8))) short bf16x8;

#define GLOAD_LDS16(g, l)                                                      \
  __builtin_amdgcn_global_load_lds(                                            \
      (const __attribute__((address_space(1))) void*)(g),                      \
      (__attribute__((address_space(3))) void*)(l), 16, 0, 0)

#define SFENCE() __builtin_amdgcn_sched_barrier(0)
#define CFENCE() asm volatile("" ::: "memory")
#define BARRIER()                                                              \
  do {                                                                         \
    SFENCE();                                                                  \
    CFENCE();                                                                  \
    __builtin_amdgcn_s_barrier();                                              \
    CFENCE();                                                                  \
    SFENCE();                                                                  \
  } while (0)
#define VMCNT(n) asm volatile("s_waitcnt vmcnt(" #n ")" ::: "memory")

// int32 in [-127,127] -> bf16 exact
__device__ __forceinline__ u16 i32_to_bf16(int v) {
  return (u16)(__float_as_uint((float)v) >> 16);
}
__device__ __forceinline__ u16 f32_to_bf16(float f) {
  __hip_bfloat16 h = __float2bfloat16(f);
  return *(u16*)&h;
}

__global__ void wconvert_kernel(const int* __restrict__ w,
                                u16* __restrict__ out, int n4) {
  int idx = blockIdx.x * blockDim.x + threadIdx.x;
  int stride = gridDim.x * blockDim.x;
  const int4* w4 = (const int4*)w;
  ushort4* o4 = (ushort4*)out;
  for (int i = idx; i < n4; i += stride) {
    int4 v = w4[i];
    ushort4 o;
    o.x = i32_to_bf16(v.x);
    o.y = i32_to_bf16(v.y);
    o.z = i32_to_bf16(v.z);
    o.w = i32_to_bf16(v.w);
    o4[i] = o;
  }
}

__global__ void xconvert_kernel(const float* __restrict__ x,
                                u16* __restrict__ out, int n4) {
  int idx = blockIdx.x * blockDim.x + threadIdx.x;
  int stride = gridDim.x * blockDim.x;
  const float4* x4 = (const float4*)x;
  ushort4* o4 = (ushort4*)out;
  for (int i = idx; i < n4; i += stride) {
    float4 v = x4[i];
    ushort4 o;
    o.x = f32_to_bf16(v.x);
    o.y = f32_to_bf16(v.y);
    o.z = f32_to_bf16(v.z);
    o.w = f32_to_bf16(v.w);
    o4[i] = o;
  }
}

// Stage one half-tile (128 rows x 64 k, bf16, 16KB) global->LDS.
// LDS dest is LINEAR (gload_lds writes base + lane*16); the st-swizzle is
// applied by permuting the GLOBAL source 16B-unit:
//   stored unit at LDS slot (row, lin) = lin ^ sigma(row),
//   sigma(row) = (row ^ (row>>2)) & 7  (r2-verified conflict-free: 0 cnt)
__device__ __forceinline__ void stage_half(const u16* __restrict__ src,
                                           u16* lds_half, int t) {
#pragma unroll
  for (int c = 0; c < 2; ++c) {
    int e = c * 4096 + t * 8;                 // per-lane linear u16 offset
    int row = c * 64 + (t >> 3);              // 0..127
    int usw = (t & 7) ^ (((t >> 3) ^ (t >> 5)) & 7);  // lin ^ sigma(row)
    int base = __builtin_amdgcn_readfirstlane(e);  // wave-uniform LDS base
    GLOAD_LDS16(src + (size_t)row * K_DIM + usw * 8, lds_half + base);
  }
}

// swizzled fragment read: tile row r (0..255), 16B-unit u (0..7)
__device__ __forceinline__ bf16x8 frag(const u16* sbuf, int r, int u) {
  return *(const bf16x8*)&sbuf[r * 64 + ((u ^ ((r ^ (r >> 2)) & 7)) << 3)];
}

// C[M,N] = X[M,K] * W[N,K]^T ; y = acc*scale[n] + bias[n], f32 out.
// 256x256 tile, BK=64, 8 waves (2M x 4N), per-wave 128x64 output.
// MERGED 4-phase K-loop (2 K-tiles/iter), ONE barrier per phase:
//   phase = { stage-issue ; ds_reads ; QUAD x2 ; [vmcnt] ; barrier }
// Safety: every ds_read is consumed by a QUAD in its own phase, so each
// wave's reads are lgkm-drained before it passes the phase-end barrier;
// any LDS region is overwrite-staged only in a LATER phase (>=1 barrier +
// 2 QUADs after its last read), and staged-data residency before reads is
// enforced by counted VMCNT + barrier at M2/M4 (same land-gating as the
// r0-r2 verified template). Removing the pre-QUAD barrier lets the
// compiler's counted lgkmcnt interleave the LDS-read drain into the MFMA
// stream instead of serializing read-window / MFMA-window per phase.
__global__ __launch_bounds__(512, 2) void qgemm8_kernel(
    const u16* __restrict__ Xb,   // bf16 [M][K]
    const u16* __restrict__ Wb,   // bf16 [N][K]
    const float* __restrict__ S,  // f32 [N]
    const float* __restrict__ Bv, // f32 [N]
    float* __restrict__ Y,        // f32 [M][N]
    int M) {
  extern __shared__ u16 lds[];
  u16* sA0 = lds;             // buf0 A [256][64]
  u16* sB0 = lds + 16384;     // buf0 B
  u16* sA1 = lds + 32768;     // buf1 A
  u16* sB1 = lds + 49152;     // buf1 B

  const int t = threadIdx.x;
  // XCD-aware swizzle (nwg = 2048, divisible by 8)
  const int bid = blockIdx.x;
  const int cpx = gridDim.x >> 3;
  const int swz = (bid & 7) * cpx + (bid >> 3);
  const int n0 = (swz & 63) * BN;  // 64 n-blocks
  const int m0 = (swz >> 6) * BM;

  const int lane = t & 63;
  const int wid = t >> 6;   // 0..7
  const int r32 = lane & 31;   // row/col within 32x32 tile
  const int hi1 = lane >> 5;   // k-half selector (0..1)
  const int wm = wid >> 2;  // 0..1 -> rows wm*128..+127
  const int wn = wid & 3;   // 0..3 -> cols wn*64..+63

  const u16* Asrc = Xb + (size_t)m0 * K_DIM;
  const u16* Bsrc = Wb + (size_t)n0 * K_DIM;

  f32x16 acc[4][2] = {};  // [row-tile 0..3][col-tile 0..1]
  bf16x8 aT[8], bT[8];    // [rt*4+ks] / [ct*4+ks], ks = 0..3 (K=16 steps)

  // 32x32x16 operand layout: lane holds row/col = lane&31,
  // k = (lane>>5)*8 + j  -> 16B unit u = ks*2 + hi1 within the 64-k row.
#define LOAD_B_CT(sb, CT)                                                      \
  _Pragma("unroll") for (int ks = 0; ks < 4; ++ks)                             \
      bT[(CT) * 4 + ks] = frag(sb, wn * 64 + (CT) * 32 + r32, ks * 2 + hi1);

#define LOAD_A(sa, HB)                                                         \
  _Pragma("unroll") for (int rt = 0; rt < 2; ++rt)                             \
  _Pragma("unroll") for (int ks = 0; ks < 4; ++ks)                             \
      aT[rt * 4 + ks] =                                                        \
          frag(sa, wm * 128 + ((HB) + rt) * 32 + r32, ks * 2 + hi1);

// one quadrant: 64 rows (HB half) x 32 cols (CT) x K=64 -> 8 MFMAs
#define QUAD(HB, CT)                                                           \
  do {                                                                         \
    __builtin_amdgcn_s_setprio(1);                                             \
    _Pragma("unroll") for (int ks = 0; ks < 4; ++ks)                           \
    _Pragma("unroll") for (int rt = 0; rt < 2; ++rt)                           \
        acc[(HB) + rt][CT] =                                                   \
            __builtin_amdgcn_mfma_f32_32x32x16_bf16(                           \
                aT[rt * 4 + ks], bT[(CT) * 4 + ks], acc[(HB) + rt][CT],        \
                0, 0, 0);                                                      \
    __builtin_amdgcn_s_setprio(0);                                             \
  } while (0)

  // ---- prologue: stage T0 fully (4 halves), then T1's B0,B1,A0 (3 halves)
  stage_half(Bsrc, sB0, t);
  stage_half(Bsrc + 128 * K_DIM, sB0 + HALF_ELEMS, t);
  stage_half(Asrc, sA0, t);
  stage_half(Asrc + 128 * K_DIM, sA0 + HALF_ELEMS, t);
  VMCNT(4);
  stage_half(Bsrc + BK, sB1, t);
  stage_half(Bsrc + 128 * K_DIM + BK, sB1 + HALF_ELEMS, t);
  stage_half(Asrc + BK, sA1, t);
  VMCNT(6);  // T0's 4 halves landed; 3 halves (T1 partial) in flight
  BARRIER();

  // ---- main loop: iteration i computes K-tiles 2i (buf0) and 2i+1 (buf1)
  // vmcnt ledger (2 instr/half, per wave): iter-start invariant = 6
  // outstanding (T1's B0,B1,A0). M1 +2 -> 8; M2 +4 -> 12, vmcnt(4) drains
  // T1's 8; M3 +4 -> 8; M4 +6 -> 14, vmcnt(6) drains Tn0's 8 -> 6 = invariant.
  for (int i = 0; i < NT / 2; ++i) {
    const int t1k = (2 * i + 1) * BK;
    const int tn0k = (2 * i + 2) * BK;
    const int tn1k = (2 * i + 3) * BK;
    const bool gn0 = (2 * i + 2) < NT;
    const bool gn1 = (2 * i + 3) < NT;

    // M1: T0 quadrants (0,0)+(0,1); stage A1 of T1 -> sA1-hi
    stage_half(Asrc + 128 * K_DIM + t1k, sA1 + HALF_ELEMS, t);
    LOAD_B_CT(sB0, 0);
    LOAD_A(sA0, 0);
    LOAD_B_CT(sB0, 1);  // overlaps QUAD(0,0) via counted lgkm
    QUAD(0, 0);
    QUAD(0, 1);
    BARRIER();

    // M2: T0 quadrants (2,0)+(2,1); stage B of Tn0 -> sB0 (dead since M1)
    if (gn0) {
      stage_half(Bsrc + tn0k, sB0, t);
      stage_half(Bsrc + 128 * K_DIM + tn0k, sB0 + HALF_ELEMS, t);
    }
    LOAD_A(sA0, 2);
    QUAD(2, 0);
    QUAD(2, 1);
    if (gn0) {
      VMCNT(4);  // T1 fully resident for M3 reads
    } else {
      VMCNT(0);
    }
    BARRIER();

    // M3: T1 quadrants (0,0)+(0,1); stage A of Tn0 -> sA0 (dead since M2)
    if (gn0) {
      stage_half(Asrc + tn0k, sA0, t);
      stage_half(Asrc + 128 * K_DIM + tn0k, sA0 + HALF_ELEMS, t);
    }
    LOAD_B_CT(sB1, 0);
    LOAD_A(sA1, 0);
    LOAD_B_CT(sB1, 1);
    QUAD(0, 0);
    QUAD(0, 1);
    BARRIER();

    // M4: T1 quadrants (2,0)+(2,1); stage B0,B1,A0 of Tn1 -> sB1, sA1-lo
    if (gn1) {
      stage_half(Bsrc + tn1k, sB1, t);
      stage_half(Bsrc + 128 * K_DIM + tn1k, sB1 + HALF_ELEMS, t);
      stage_half(Asrc + tn1k, sA1, t);
    }
    LOAD_A(sA1, 2);
    QUAD(2, 0);
    QUAD(2, 1);
    if (gn1) {
      VMCNT(6);  // Tn0 fully resident for next iteration's M1 reads
    } else {
      VMCNT(0);
    }
    BARRIER();
  }

  // ---- epilogue: y = acc * scale[n] + bias[n], f32 store
  // 32x32 C/D layout: col = lane&31, row = (reg&3) + 8*(reg>>2) + 4*(lane>>5)
#pragma unroll
  for (int ct = 0; ct < 2; ++ct) {
    int n = n0 + wn * 64 + ct * 32 + r32;
    float sc = S[n];
    float bv = Bv[n];
#pragma unroll
    for (int mi = 0; mi < 4; ++mi) {
#pragma unroll
      for (int reg = 0; reg < 16; ++reg) {
        int m = m0 + wm * 128 + mi * 32 + (reg & 3) + 8 * (reg >> 2) + 4 * hi1;
        Y[(size_t)m * N_DIM + n] = acc[mi][ct][reg] * sc + bv;
      }
    }
  }
#undef LOAD_A
#undef LOAD_B_CT
#undef QUAD
}

// ---- fallback (ws too small): serial 128^2 with inline convert (r3-verified
// structure, minus pre-conversion)
__global__ __launch_bounds__(256) void qgemm_fb_kernel(
    const float* __restrict__ Xf, const int* __restrict__ Wi,
    const float* __restrict__ S, const float* __restrict__ Bv,
    float* __restrict__ Y, int M) {
  __shared__ u16 As[128 * 64];
  __shared__ u16 Bs[128 * 64];
  const int t = threadIdx.x;
  const int bid = blockIdx.x;
  const int n0 = (bid & 127) * 128;
  const int m0 = (bid >> 7) * 128;
  const int lane = t & 63;
  const int wid = t >> 6;
  const int r16 = lane & 15;
  const int hi4 = lane >> 4;
  const int wm = wid >> 1;
  const int wn = wid & 1;
  f32x4 acc[4][4] = {};
  for (int kt = 0; kt < K_DIM; kt += 64) {
#pragma unroll
    for (int c = 0; c < 8; ++c) {
      int h = c * 1024 + t * 4;
      int row = h >> 6;
      int col = h & 63;
      float4 v = *(const float4*)(Xf + (size_t)(m0 + row) * K_DIM + kt + col);
      ushort4 o;
      o.x = f32_to_bf16(v.x); o.y = f32_to_bf16(v.y);
      o.z = f32_to_bf16(v.z); o.w = f32_to_bf16(v.w);
      *(ushort4*)&As[h] = o;
      int4 w = *(const int4*)(Wi + (size_t)(n0 + row) * K_DIM + kt + col);
      ushort4 ow;
      ow.x = i32_to_bf16(w.x); ow.y = i32_to_bf16(w.y);
      ow.z = i32_to_bf16(w.z); ow.w = i32_to_bf16(w.w);
      *(ushort4*)&Bs[h] = ow;
    }
    __syncthreads();
#pragma unroll
    for (int kk = 0; kk < 64; kk += 32) {
      bf16x8 af[4], bf[4];
#pragma unroll
      for (int mi = 0; mi < 4; ++mi)
        af[mi] = *(const bf16x8*)&As[(wm * 64 + mi * 16 + r16) * 64 + kk + hi4 * 8];
#pragma unroll
      for (int ni = 0; ni < 4; ++ni)
        bf[ni] = *(const bf16x8*)&Bs[(wn * 64 + ni * 16 + r16) * 64 + kk + hi4 * 8];
#pragma unroll
      for (int mi = 0; mi < 4; ++mi)
#pragma unroll
        for (int ni = 0; ni < 4; ++ni)
          acc[mi][ni] = __builtin_amdgcn_mfma_f32_16x16x32_bf16(
              af[mi], bf[ni], acc[mi][ni], 0, 0, 0);
    }
    __syncthreads();
  }
#pragma unroll
  for (int ni = 0; ni < 4; ++ni) {
    int n = n0 + wn * 64 + ni * 16 + r16;
    float sc = S[n], bv = Bv[n];
#pragma unroll
    for (int mi = 0; mi < 4; ++mi)
#pragma unroll
      for (int r = 0; r < 4; ++r) {
        int m = m0 + wm * 64 + mi * 16 + hi4 * 4 + r;
        Y[(size_t)m * N_DIM + n] = acc[mi][ni][r] * sc + bv;
      }
  }
}

extern "C" void kernel_launch(void* const* d_in, const int* in_sizes, int n_in,
                              void* d_out, int out_size, void* d_ws,
                              size_t ws_size, hipStream_t stream) {
  const float* x = (const float*)d_in[0];  // fp16 promoted to f32 by harness
  const int* wgt = (const int*)d_in[1];    // int8 promoted to int32
  const float* s = (const float*)d_in[2];
  const float* b = (const float*)d_in[3];
  float* y = (float*)d_out;

  const int M = in_sizes[0] / K_DIM;  // 8192
  const size_t wcount = (size_t)N_DIM * K_DIM;
  const size_t xcount = (size_t)in_sizes[0];
  const size_t need = (wcount + xcount) * sizeof(u16);

  if (ws_size >= need && (M % BM) == 0) {
    u16* wb = (u16*)d_ws;
    u16* xb = wb + wcount;
    wconvert_kernel<<<2048, 256, 0, stream>>>(wgt, wb, (int)(wcount / 4));
    xconvert_kernel<<<2048, 256, 0, stream>>>(x, xb, (int)(xcount / 4));
    hipFuncSetAttribute((const void*)qgemm8_kernel,
                        hipFuncAttributeMaxDynamicSharedMemorySize, 131072);
    dim3 grid((N_DIM / BN) * (M / BM));  // 2048
    qgemm8_kernel<<<grid, 512, 131072, stream>>>(xb, wb, s, b, y, M);
  } else {
    dim3 grid((N_DIM / 128) * (M / 128));
    qgemm_fb_kernel<<<grid, 256, 0, stream>>>(x, wgt, s, b, y, M);
  }
}